// Round 1
// baseline (308.143 us; speedup 1.0000x reference)
//
#include <hip/hip_runtime.h>

// Problem dims (fixed by the reference)
#define B_ 32
#define T_ 168
#define M_ 1024
#define A_ 8
#define H_ 64

// ---------------------------------------------------------------------------
// Key insight: the LSTM state (hn, cn) is carried by the scan but NEVER feeds
// the output. out[b,t,m] depends only on x[b,t,m,:] and per-m constants:
//
//   out = dot(x, v_m) + mn*c1_m + mx*c2_m + c3_m
// where
//   v_m[a] = sum_h assoc_w[m,a,h] * dense_w[m,h]
//   sb     = sum_h assoc_b[m,h]   * dense_w[m,h]
//   Sd     = sum_h dense_w[m,h]
//   c1 = Sd - sum_a v_m[a] - sb ;  c2 = sb ;  c3 = dense_b[m]
//
// (the (mx-mn) normalization cancels algebraically against inverse-norm)
// ---------------------------------------------------------------------------

// table layout (SoA, coalesced by m): v[a]*M for a=0..7, c1*M, c2*M, c3*M
__global__ __launch_bounds__(256) void precompute_kernel(
    const float* __restrict__ assoc_w,  // [M,A,H]
    const float* __restrict__ assoc_b,  // [M,H]
    const float* __restrict__ dense_w,  // [M,H,1]
    const float* __restrict__ dense_b,  // [M,1]
    float* __restrict__ table)          // [11*M]
{
    const int wave = threadIdx.x >> 6;           // 4 waves per block
    const int lane = threadIdx.x & 63;           // lane == h (H == 64)
    const int m    = blockIdx.x * 4 + wave;
    if (m >= M_) return;

    const float dw = dense_w[m * H_ + lane];
    const float ab = assoc_b[m * H_ + lane];

    float v[A_];
#pragma unroll
    for (int a = 0; a < A_; ++a)
        v[a] = assoc_w[(m * A_ + a) * H_ + lane] * dw;
    float sb = ab * dw;
    float sd = dw;

    // butterfly wave reduction (wave = 64 lanes)
#pragma unroll
    for (int off = 32; off >= 1; off >>= 1) {
#pragma unroll
        for (int a = 0; a < A_; ++a) v[a] += __shfl_xor(v[a], off, 64);
        sb += __shfl_xor(sb, off, 64);
        sd += __shfl_xor(sd, off, 64);
    }

    if (lane == 0) {
        float sv = 0.f;
#pragma unroll
        for (int a = 0; a < A_; ++a) { table[a * M_ + m] = v[a]; sv += v[a]; }
        table[8 * M_ + m]  = sd - sv - sb;   // c1 (mn coefficient)
        table[9 * M_ + m]  = sb;             // c2 (mx coefficient)
        table[10 * M_ + m] = dense_b[m];     // c3
    }
}

// One thread per output element (b,t,m). idx = (b*T+t)*M + m.
// x reads: 32B/thread, consecutive threads -> consecutive m -> fully coalesced.
__global__ __launch_bounds__(256) void main_kernel(
    const float* __restrict__ x,      // [B,T,M,A]
    const float* __restrict__ table,  // [11*M]
    float* __restrict__ out,          // [B,T,M]
    int n)
{
    const int idx = blockIdx.x * 256 + threadIdx.x;
    if (idx >= n) return;
    const int m = idx & (M_ - 1);

    const float4* xp = (const float4*)(x + (size_t)idx * A_);
    const float4 x0 = xp[0];
    const float4 x1 = xp[1];

    const float mn = fminf(fminf(fminf(x0.x, x0.y), fminf(x0.z, x0.w)),
                           fminf(fminf(x1.x, x1.y), fminf(x1.z, x1.w)));
    const float mx = fmaxf(fmaxf(fmaxf(x0.x, x0.y), fmaxf(x0.z, x0.w)),
                           fmaxf(fmaxf(x1.x, x1.y), fmaxf(x1.z, x1.w)));

    float dot;
    dot  = x0.x * table[0 * M_ + m];
    dot += x0.y * table[1 * M_ + m];
    dot += x0.z * table[2 * M_ + m];
    dot += x0.w * table[3 * M_ + m];
    dot += x1.x * table[4 * M_ + m];
    dot += x1.y * table[5 * M_ + m];
    dot += x1.z * table[6 * M_ + m];
    dot += x1.w * table[7 * M_ + m];

    out[idx] = dot + mn * table[8 * M_ + m] + mx * table[9 * M_ + m]
                   + table[10 * M_ + m];
}

// Fallback (only if ws_size is too small to hold the 44 KB table):
// recompute coefficients per thread. Slow but correct; branch is on ws_size,
// which is constant across calls, so graph capture sees identical work.
__global__ __launch_bounds__(256) void fused_fallback_kernel(
    const float* __restrict__ x,
    const float* __restrict__ assoc_w,
    const float* __restrict__ assoc_b,
    const float* __restrict__ dense_w,
    const float* __restrict__ dense_b,
    float* __restrict__ out,
    int n)
{
    const int idx = blockIdx.x * 256 + threadIdx.x;
    if (idx >= n) return;
    const int m = idx & (M_ - 1);

    float v[A_] = {0.f};
    float sb = 0.f, sd = 0.f;
    for (int h = 0; h < H_; ++h) {
        const float dw = dense_w[m * H_ + h];
        sd += dw;
        sb += assoc_b[m * H_ + h] * dw;
#pragma unroll
        for (int a = 0; a < A_; ++a)
            v[a] += assoc_w[(m * A_ + a) * H_ + h] * dw;
    }
    float sv = 0.f;
#pragma unroll
    for (int a = 0; a < A_; ++a) sv += v[a];

    const float4* xp = (const float4*)(x + (size_t)idx * A_);
    const float4 x0 = xp[0];
    const float4 x1 = xp[1];
    const float xs[A_] = {x0.x, x0.y, x0.z, x0.w, x1.x, x1.y, x1.z, x1.w};

    float mn = xs[0], mx = xs[0], dot = 0.f;
#pragma unroll
    for (int a = 0; a < A_; ++a) {
        mn = fminf(mn, xs[a]);
        mx = fmaxf(mx, xs[a]);
        dot += xs[a] * v[a];
    }
    out[idx] = dot + mn * (sd - sv - sb) + mx * sb + dense_b[m];
}

extern "C" void kernel_launch(void* const* d_in, const int* in_sizes, int n_in,
                              void* d_out, int out_size, void* d_ws, size_t ws_size,
                              hipStream_t stream)
{
    const float* input   = (const float*)d_in[0];
    const float* assoc_w = (const float*)d_in[1];
    const float* assoc_b = (const float*)d_in[2];
    // d_in[3..6] = w_ih, w_hh, b_ih, b_hh -> dead w.r.t. the output
    const float* dense_w = (const float*)d_in[7];
    const float* dense_b = (const float*)d_in[8];
    float* out = (float*)d_out;

    const int n = out_size;  // B*T*M = 5,505,024
    const size_t need = (size_t)(11 * M_) * sizeof(float);

    if (ws_size >= need) {
        float* table = (float*)d_ws;
        precompute_kernel<<<M_ / 4, 256, 0, stream>>>(assoc_w, assoc_b,
                                                      dense_w, dense_b, table);
        main_kernel<<<(n + 255) / 256, 256, 0, stream>>>(input, table, out, n);
    } else {
        fused_fallback_kernel<<<(n + 255) / 256, 256, 0, stream>>>(
            input, assoc_w, assoc_b, dense_w, dense_b, out, n);
    }
}